// Round 14
// baseline (523.901 us; speedup 1.0000x reference)
//
#include <hip/hip_runtime.h>

#define NN 100000
#define NE 1600000
#define BN_EPS 1e-5f
#define CSHIFT 9
#define NBC ((NN + 511) >> CSHIFT)   // 196 coarse buckets of 512 nodes
#define CAPC 10240                   // slots per coarse bucket (mean 8163)
#define EPB1 4096
#define NBLK1 ((NE + EPB1 - 1)/EPB1) // 391 pass-1 blocks
#define NTILES ((NN + 63)/64)        // 1563 row tiles
#define GGRID 521                    // 521*3 = 1563 exactly
#define NPAGE 64                     // stats partial pages
#define SLNN ((size_t)NN*2)          // uint4 per slice region (NN * 32B)

typedef short bf16x8 __attribute__((ext_vector_type(8)));
typedef float f32x4  __attribute__((ext_vector_type(4)));

__constant__ float c_wtab[26] = {0.7f,0.9f,0.7f,0.9f,0.3f,0.7f,0.3f,0.9f,0.3f,0.3f,0.9f,0.7f,0.1f,
                                 0.9f,0.5f,0.9f,0.5f,0.5f,0.1f,0.3f,0.7f,0.9f,0.9f,0.9f,0.9f,0.9f};

__device__ __forceinline__ unsigned f2bf(float f){
    unsigned u = __float_as_uint(f);
    return (u + 0x7fffu + ((u >> 16) & 1u)) >> 16;   // round-to-nearest-even
}
__device__ __forceinline__ float bflo(unsigned v){ return __uint_as_float(v << 16); }
__device__ __forceinline__ float bfhi(unsigned v){ return __uint_as_float(v & 0xffff0000u); }

// ---- weight prep: transpose + bf16 (Bt[col][k] layout for MFMA B-operand) ----
__global__ void k_prepw(const float* __restrict__ w0, const float* __restrict__ w1,
                        const float* __restrict__ w2, const float* __restrict__ wfc,
                        unsigned short* __restrict__ wt){
    int i = blockIdx.x*256 + threadIdx.x;
    if (i < 4096){                       // w0t: [128 cols][32 k], k>=26 zero
        int c = i >> 5, k = i & 31;
        float v = (k < 26) ? w0[k*128 + c] : 0.f;
        wt[i] = (unsigned short)f2bf(v);
    } else if (i < 20480){               // w1t: [128][128]
        int j = i - 4096; int c = j >> 7, k = j & 127;
        wt[i] = (unsigned short)f2bf(w1[k*128 + c]);
    } else if (i < 36864){               // w2t: [128][128]
        int j = i - 20480; int c = j >> 7, k = j & 127;
        wt[i] = (unsigned short)f2bf(w2[k*128 + c]);
    } else if (i < 45056){               // wfct: [64][128]
        int j = i - 36864; int c = j >> 7, k = j & 127;
        wt[i] = (unsigned short)f2bf(wfc[k*64 + c]);
    }
}

// ---- cursor init: per-coarse-bucket region bases ----
__global__ void k_init(unsigned* __restrict__ gcurD, unsigned* __restrict__ gcurS){
    int i = blockIdx.x*256 + threadIdx.x;
    if (i < NBC){ gcurD[i] = (unsigned)i*CAPC; gcurS[i] = (unsigned)i*CAPC; }
}

// ---- pass 1: coarse radix scatter, run-reserved contiguous writes ----
__global__ __launch_bounds__(512) void k_radix1(const int* __restrict__ src,
                                                const int* __restrict__ dst,
                                                unsigned* __restrict__ gcurD,
                                                unsigned* __restrict__ gcurS,
                                                unsigned* __restrict__ pairs,
                                                unsigned short* __restrict__ tok){
    __shared__ unsigned hD[NBC], hS[NBC];
    int tid = threadIdx.x;
    for (int i = tid; i < NBC; i += 512){ hD[i] = 0u; hS[i] = 0u; }
    __syncthreads();
    int base = blockIdx.x*EPB1;
    int n = NE - base; if (n > EPB1) n = EPB1;
    for (int k = tid; k < n; k += 512){
        atomicAdd(&hD[(unsigned)dst[base+k] >> CSHIFT], 1u);
        atomicAdd(&hS[(unsigned)src[base+k] >> CSHIFT], 1u);
    }
    __syncthreads();
    for (int i = tid; i < NBC; i += 512){
        unsigned c = hD[i];
        hD[i] = c ? atomicAdd(&gcurD[i], c) : 0u;
        c = hS[i];
        hS[i] = c ? atomicAdd(&gcurS[i], c) : 0u;
    }
    __syncthreads();
    for (int k = tid; k < n; k += 512){
        int d = dst[base+k], s = src[base+k];
        unsigned bb = (unsigned)d >> CSHIFT;
        unsigned p = atomicAdd(&hD[bb], 1u);
        if (p < (bb+1)*CAPC)
            pairs[p] = ((unsigned)(d & 511) << 17) | (unsigned)s;
        bb = (unsigned)s >> CSHIFT;
        p = atomicAdd(&hS[bb], 1u);
        if (p < (bb+1)*CAPC)
            tok[p] = (unsigned short)(s & 511);
    }
}

// ---- pass 2: block-per-coarse-bucket -> exact CSR + degi + dego (no global atomics) ----
__global__ __launch_bounds__(1024) void k_radix2(const unsigned* __restrict__ gcurD,
                                                 const unsigned* __restrict__ gcurS,
                                                 const unsigned* __restrict__ pairs,
                                                 const unsigned short* __restrict__ tok,
                                                 int* __restrict__ csr,
                                                 unsigned* __restrict__ offs,
                                                 unsigned* __restrict__ degi,
                                                 unsigned* __restrict__ dego){
    __shared__ unsigned cnt[512], cur[512], scnt[512];
    int b = blockIdx.x, tid = threadIdx.x;
    if (tid < 512){ cnt[tid] = 0u; scnt[tid] = 0u; }
    __syncthreads();
    unsigned baseC = (unsigned)b*CAPC;
    unsigned nD = gcurD[b] - baseC; if (nD > CAPC) nD = CAPC;
    unsigned nS = gcurS[b] - baseC; if (nS > CAPC) nS = CAPC;
    for (unsigned i = tid; i < nD; i += 1024)
        atomicAdd(&cnt[pairs[baseC + i] >> 17], 1u);
    for (unsigned i = tid; i < nS; i += 1024)
        atomicAdd(&scnt[tok[baseC + i]], 1u);
    __syncthreads();
    if (tid < 512) cur[tid] = cnt[tid];
    __syncthreads();
    for (int o = 1; o < 512; o <<= 1){
        unsigned x = 0;
        if (tid < 512 && tid >= o) x = cur[tid - o];
        __syncthreads();
        if (tid < 512) cur[tid] += x;
        __syncthreads();
    }
    if (tid < 512){
        unsigned ex = cur[tid] - cnt[tid];   // exclusive prefix
        int node = (b << CSHIFT) + tid;
        if (node < NN){
            offs[node] = baseC + ex;
            degi[node] = cnt[tid];
            dego[node] = scnt[tid];
        }
        cur[tid] = ex;                       // becomes placement cursor
    }
    __syncthreads();
    for (unsigned i = tid; i < nD; i += 1024){
        unsigned pr = pairs[baseC + i];
        unsigned p = atomicAdd(&cur[pr >> 17], 1u);
        csr[baseC + p] = (int)(pr & 0x1FFFFu);
    }
}

// ------- per-node: norms + argmax weight + xn0 = h*nsrc -> bf16 packed [N,32] -------
__global__ void k_node(const float* __restrict__ h, const unsigned* __restrict__ dego,
                       const unsigned* __restrict__ degi, float* __restrict__ nsrc,
                       float* __restrict__ ndst, float* __restrict__ outw,
                       unsigned* __restrict__ xn0){
    int i = blockIdx.x*blockDim.x + threadIdx.x;
    if (i < NN){
        float d0 = (float)dego[i]; d0 = d0 < 1.f ? 1.f : d0;
        float d1 = (float)degi[i]; d1 = d1 < 1.f ? 1.f : d1;
        float ns = rsqrtf(d0);
        nsrc[i] = ns;
        ndst[i] = rsqrtf(d1);
        float row[26];
        #pragma unroll
        for (int c = 0; c < 26; ++c) row[c] = h[(size_t)i*26 + c];
        float best = row[0]; int bi = 0;
        #pragma unroll
        for (int c = 1; c < 26; ++c){ if (row[c] > best){ best = row[c]; bi = c; } }
        outw[i] = c_wtab[bi];
        #pragma unroll
        for (int d = 0; d < 13; ++d)
            xn0[(size_t)i*16 + d] = f2bf(row[2*d]*ns) | (f2bf(row[2*d+1]*ns) << 16);
        #pragma unroll
        for (int d = 13; d < 16; ++d) xn0[(size_t)i*16 + d] = 0u;
    }
}

// ------- layer-0 aggregation: bf16 [N,32] gather (4 lanes/row x 16 groups) -> bf16 [N,32] -------
__global__ __launch_bounds__(64) void k_agg0(const uint4* __restrict__ xn,
                                             const unsigned* __restrict__ offs,
                                             const unsigned* __restrict__ degi,
                                             const int* __restrict__ csr,
                                             uint4* __restrict__ agg){
    int node = blockIdx.x;
    int lane = threadIdx.x;
    int g = lane >> 2, q = lane & 3;     // 16 edge-groups x 4 uint4-slots
    unsigned beg = offs[node], end = beg + degi[node];
    float a[8];
    #pragma unroll
    for (int j = 0; j < 8; ++j) a[j] = 0.f;
    for (unsigned e = beg + (unsigned)g; e < end; e += 16){
        uint4 v = xn[(size_t)csr[e]*4 + q];
        a[0] += bflo(v.x); a[1] += bfhi(v.x);
        a[2] += bflo(v.y); a[3] += bfhi(v.y);
        a[4] += bflo(v.z); a[5] += bfhi(v.z);
        a[6] += bflo(v.w); a[7] += bfhi(v.w);
    }
    #pragma unroll
    for (int j = 0; j < 8; ++j){
        a[j] += __shfl_xor(a[j], 4);
        a[j] += __shfl_xor(a[j], 8);
        a[j] += __shfl_xor(a[j], 16);
        a[j] += __shfl_xor(a[j], 32);
    }
    if (g == 0){
        uint4 o;
        o.x = f2bf(a[0]) | (f2bf(a[1]) << 16);
        o.y = f2bf(a[2]) | (f2bf(a[3]) << 16);
        o.z = f2bf(a[4]) | (f2bf(a[5]) << 16);
        o.w = f2bf(a[6]) | (f2bf(a[7]) << 16);
        agg[(size_t)node*4 + q] = o;
    }
}

// ---- layers 1/2 aggregation: XCD-sliced channel gather ----
// Features slice-major: xnS[slice][node][32B]. slice = blockIdx%8 (round-robin -> XCD-local L2).
// Block: 256 thr = 4 waves x 2 nodes; per node 16 edges x 2 lanes (uint4 each).
__global__ __launch_bounds__(256) void k_agg_bf(const uint4* __restrict__ xnS,
                                                const unsigned* __restrict__ offs,
                                                const unsigned* __restrict__ degi,
                                                const int* __restrict__ csr,
                                                uint4* __restrict__ aggS){
    const int slice = blockIdx.x & 7;
    const int ng = blockIdx.x >> 3;          // node group of 8
    const int tid = threadIdx.x;
    const int w = tid >> 6, lane = tid & 63;
    const int half = lane >> 5;              // node within wave
    const int node = ng*8 + w*2 + half;
    const int el = (lane & 31) >> 1;         // edge slot 0..15
    const int q = lane & 1;                  // uint4 within 32B slice
    const uint4* base = xnS + (size_t)slice*SLNN;
    unsigned beg = offs[node], end = beg + degi[node];
    float a[8];
    #pragma unroll
    for (int j = 0; j < 8; ++j) a[j] = 0.f;
    for (unsigned e = beg + (unsigned)el; e < end; e += 16){
        int s = csr[e];
        uint4 v = base[(size_t)s*2 + q];
        a[0] += bflo(v.x); a[1] += bfhi(v.x);
        a[2] += bflo(v.y); a[3] += bfhi(v.y);
        a[4] += bflo(v.z); a[5] += bfhi(v.z);
        a[6] += bflo(v.w); a[7] += bfhi(v.w);
    }
    // reduce over the 16 edge slots (lane bits 1..4)
    #pragma unroll
    for (int j = 0; j < 8; ++j){
        a[j] += __shfl_xor(a[j], 2);
        a[j] += __shfl_xor(a[j], 4);
        a[j] += __shfl_xor(a[j], 8);
        a[j] += __shfl_xor(a[j], 16);
    }
    if (el == 0){
        uint4 o;
        o.x = f2bf(a[0]) | (f2bf(a[1]) << 16);
        o.y = f2bf(a[2]) | (f2bf(a[3]) << 16);
        o.z = f2bf(a[4]) | (f2bf(a[5]) << 16);
        o.w = f2bf(a[6]) | (f2bf(a[7]) << 16);
        aggS[(size_t)slice*SLNN + (size_t)node*2 + q] = o;
    }
}

// ---------------- MFMA GEMM (grid-strided): Z = A(bf16) @ Bt^T (*ndst) + bias ----------------
// SLICED: A stored slice-major [8][NN][32B] (CIN=128 only).
template<int CIN, int COUT, bool STATS, bool NDST, bool F32OUT, bool SLICED>
__global__ __launch_bounds__(256) void k_gemm_mfma(const unsigned short* __restrict__ A,
                                                   const unsigned short* __restrict__ Bt,
                                                   const float* __restrict__ bias,
                                                   const float* __restrict__ ndst,
                                                   void* __restrict__ Zv,
                                                   float* __restrict__ part){
    constexpr int KD4 = CIN/8;    // uint4 per row
    constexpr int NT = COUT/16;   // 16-col tiles per wave
    __shared__ char sA[64*CIN*2];
    __shared__ char sB[COUT*CIN*2];
    __shared__ float sS[2][COUT];
    float* Zf = (float*)Zv;
    unsigned short* Zh = (unsigned short*)Zv;
    const int tid = threadIdx.x;
    const int w = tid >> 6, lane = tid & 63;
    const int lrow = lane & 15, kg = lane >> 4;

    const uint4* B4 = (const uint4*)Bt;
    for (int i = tid; i < COUT*KD4; i += 256){
        int cc = i/KD4, c4 = i - cc*KD4;
        *(uint4*)(sB + ((cc*CIN*2 + c4*16) ^ ((cc&7)<<4))) = B4[i];
    }
    if (STATS){
        for (int i = tid; i < 2*COUT; i += 256) (&sS[0][0])[i] = 0.f;
    }

    float cs[NT], cq[NT];
    #pragma unroll
    for (int n = 0; n < NT; ++n){ cs[n] = 0.f; cq[n] = 0.f; }

    const uint4* A4 = (const uint4*)A;
    const uint4 z4 = make_uint4(0,0,0,0);
    for (int t = blockIdx.x; t < NTILES; t += GGRID){
        const int row0 = t*64;
        for (int i = tid; i < 64*KD4; i += 256){
            int r = i/KD4, c4 = i - r*KD4;
            int gr = row0 + r;
            uint4 v;
            if (gr < NN){
                if (SLICED) v = A4[(size_t)(c4 >> 1)*SLNN + (size_t)gr*2 + (c4 & 1)];
                else        v = A4[(size_t)gr*KD4 + c4];
            } else v = z4;
            *(uint4*)(sA + ((r*CIN*2 + c4*16) ^ ((r&7)<<4))) = v;
        }
        __syncthreads();
        f32x4 acc[NT];
        #pragma unroll
        for (int n = 0; n < NT; ++n) acc[n] = (f32x4){0.f,0.f,0.f,0.f};
        const int arow = w*16 + lrow;
        #pragma unroll
        for (int kk = 0; kk < CIN/32; ++kk){
            const int kb = kk*64 + kg*16;
            bf16x8 af = *(const bf16x8*)(sA + ((arow*CIN*2 + kb) ^ ((arow&7)<<4)));
            #pragma unroll
            for (int n = 0; n < NT; ++n){
                int bc = n*16 + lrow;
                bf16x8 bv = *(const bf16x8*)(sB + ((bc*CIN*2 + kb) ^ ((bc&7)<<4)));
                acc[n] = __builtin_amdgcn_mfma_f32_16x16x32_bf16(af, bv, acc[n], 0, 0, 0);
            }
        }
        // epilogue: C/D mapping col=lane&15, row=(lane>>4)*4+j  [m89-verified]
        int grow[4]; float nm[4]; bool val[4];
        #pragma unroll
        for (int j = 0; j < 4; ++j){
            grow[j] = row0 + w*16 + kg*4 + j;
            val[j]  = grow[j] < NN;
            nm[j]   = (NDST && val[j]) ? ndst[grow[j]] : 1.f;
        }
        #pragma unroll
        for (int n = 0; n < NT; ++n){
            int gcol = n*16 + lrow;
            float bv = bias[gcol];
            #pragma unroll
            for (int j = 0; j < 4; ++j){
                float z = acc[n][j]*nm[j] + bv;
                if (val[j]){
                    if (F32OUT) Zf[(size_t)grow[j]*COUT + gcol] = z;
                    else        Zh[(size_t)grow[j]*COUT + gcol] = (unsigned short)f2bf(z);
                    if (STATS){ cs[n] += z; cq[n] += z*z; }
                }
            }
        }
        __syncthreads();
    }
    if (STATS){
        #pragma unroll
        for (int n = 0; n < NT; ++n){
            float s = cs[n], q = cq[n];
            s += __shfl_xor(s, 16); s += __shfl_xor(s, 32);
            q += __shfl_xor(q, 16); q += __shfl_xor(q, 32);
            if (kg == 0){
                atomicAdd(&sS[0][n*16 + lrow], s);
                atomicAdd(&sS[1][n*16 + lrow], q);
            }
        }
        __syncthreads();
        float* pg = part + (size_t)(blockIdx.x & (NPAGE-1))*2*COUT;
        for (int i = tid; i < 2*COUT; i += 256)
            atomicAdd(&pg[i], (&sS[0][0])[i]);
    }
}

// ---------------- BN finalize: reduce partial pages -> scale/shift ----------------
__global__ void k_bnfin(const float* __restrict__ part, float* __restrict__ stats,
                        const float* __restrict__ g, const float* __restrict__ bt){
    int c = threadIdx.x;  // 128
    float s = 0.f, q = 0.f;
    #pragma unroll 8
    for (int p = 0; p < NPAGE; ++p){
        s += part[p*256 + c];
        q += part[p*256 + 128 + c];
    }
    float mu  = s / (float)NN;
    float var = q / (float)NN - mu*mu;
    if (var < 0.f) var = 0.f;
    float sc = g[c] * rsqrtf(var + BN_EPS);
    stats[256 + c] = sc;
    stats[384 + c] = bt[c] - mu*sc;
}

// ------- BN apply + ReLU (+ optional *nsrc): bf16 Z (node-major) -> bf16 slice-major -------
__global__ void k_bnapply_bf(const unsigned* __restrict__ Xb, const float* __restrict__ stats,
                             const float* __restrict__ nsrc, unsigned* __restrict__ outS){
    int idx = blockIdx.x*blockDim.x + threadIdx.x;
    if (idx < NN*64){
        int d = idx & 63;
        int node = idx >> 6;
        int c0 = d << 1;
        unsigned v = Xb[idx];            // bf16 pair: cols (2d, 2d+1)
        float v0 = bflo(v)*stats[256 + c0]     + stats[384 + c0];
        float v1 = bfhi(v)*stats[256 + c0 + 1] + stats[384 + c0 + 1];
        float ns = nsrc ? nsrc[node] : 1.f;
        v0 = v0 > 0.f ? v0*ns : 0.f;
        v1 = v1 > 0.f ? v1*ns : 0.f;
        int slice = d >> 3, dd = d & 7;  // 8 dwords (16 ch) per slice
        outS[(size_t)slice*NN*8 + (size_t)node*8 + dd] = f2bf(v0) | (f2bf(v1) << 16);
    }
}

extern "C" void kernel_launch(void* const* d_in, const int* in_sizes, int n_in,
                              void* d_out, int out_size, void* d_ws, size_t ws_size,
                              hipStream_t stream) {
    const float* h   = (const float*)d_in[0];
    const int*   src = (const int*)d_in[1];
    const int*   dst = (const int*)d_in[2];
    const float* w0  = (const float*)d_in[3];
    const float* b0  = (const float*)d_in[4];
    const float* w1  = (const float*)d_in[5];
    const float* b1  = (const float*)d_in[6];
    const float* w2  = (const float*)d_in[7];
    const float* b2  = (const float*)d_in[8];
    const float* g0  = (const float*)d_in[9];
    const float* bt0 = (const float*)d_in[10];
    const float* g1  = (const float*)d_in[11];
    const float* bt1 = (const float*)d_in[12];
    const float* g2  = (const float*)d_in[13];
    const float* bt2 = (const float*)d_in[14];
    const float* wfc = (const float*)d_in[15];
    const float* bfc = (const float*)d_in[16];

    float* out   = (float*)d_out;                     // [NN,64]
    float* out_w = out + (size_t)NN*64;               // [NN,1]

    char* ws = (char*)d_ws;
    size_t off = 0;
    auto alloc = [&](size_t b){ size_t p = off; off += (b + 255) & ~(size_t)255; return ws + p; };

    unsigned*       dego    = (unsigned*)alloc((size_t)NN*4);
    unsigned*       degi    = (unsigned*)alloc((size_t)NN*4);
    float*          nsrc    = (float*)   alloc((size_t)NN*4);
    float*          ndst    = (float*)   alloc((size_t)NN*4);
    unsigned*       offsets = (unsigned*)alloc((size_t)NN*4);
    unsigned*       gcurD   = (unsigned*)alloc((size_t)NBC*4);
    unsigned*       gcurS   = (unsigned*)alloc((size_t)NBC*4);
    float*          stats   = (float*)   alloc(3*512*4);            // scale/shift per layer
    float*          spart   = (float*)   alloc(3*(size_t)NPAGE*256*4); // stats partial pages
    unsigned short* wt      = (unsigned short*)alloc(45056*2);  // bf16 transposed weights
    int*            csr     = (int*)     alloc((size_t)NBC*CAPC*4);   // 8 MB exact CSR
    unsigned*       xn0     = (unsigned*)alloc((size_t)NN*16*4);      // bf16 [N,32] scaled h
    unsigned short* bufA    = (unsigned short*)alloc((size_t)NN*128*2); // GEMM out (bf16 pre-BN)
    float*          bufB    = (float*)   alloc((size_t)NN*128*4);   // radix scratch / agg alias
    unsigned*       bufC    = (unsigned*)alloc((size_t)NN*64*4);    // bf16 features (slice-major)
    (void)ws_size; (void)in_sizes; (void)n_in; (void)out_size;

    unsigned*       pairs = (unsigned*)bufB;                          // 8 MB
    unsigned short* tok   = (unsigned short*)((char*)bufB + (size_t)NBC*CAPC*4); // 4 MB
    uint4*          aggB  = (uint4*)bufB;   // agg outputs (radix scratch dead by then)

    hipMemsetAsync(spart, 0, 3*(size_t)NPAGE*256*4, stream);

    // ---- build: weight prep + 2-pass coarse radix -> exact CSR + degrees ----
    k_prepw<<<176, 256, 0, stream>>>(w0, w1, w2, wfc, wt);
    k_init<<<1, 256, 0, stream>>>(gcurD, gcurS);
    k_radix1<<<NBLK1, 512, 0, stream>>>(src, dst, gcurD, gcurS, pairs, tok);
    k_radix2<<<NBC, 1024, 0, stream>>>(gcurD, gcurS, pairs, tok, csr, offsets, degi, dego);
    k_node<<<(NN + 255)/256, 256, 0, stream>>>(h, dego, degi, nsrc, ndst, out_w, xn0);

    // ---- layer 0: bf16 gather-agg (node-major) -> gemm 32x128 ----
    k_agg0<<<NN, 64, 0, stream>>>((const uint4*)xn0, offsets, degi, csr, aggB);
    k_gemm_mfma<32,128,true,true,false,false><<<GGRID, 256, 0, stream>>>((const unsigned short*)aggB, wt, b0,
                                                                         ndst, bufA, spart + 0*NPAGE*256);
    k_bnfin<<<1, 128, 0, stream>>>(spart + 0*NPAGE*256, stats + 0*512, g0, bt0);
    k_bnapply_bf<<<(NN*64 + 255)/256, 256, 0, stream>>>((unsigned*)bufA, stats + 0*512, nsrc, bufC);

    // ---- layer 1: XCD-sliced gather-agg -> gemm (sliced A) ----
    k_agg_bf<<<NN, 256, 0, stream>>>((const uint4*)bufC, offsets, degi, csr, aggB);
    k_gemm_mfma<128,128,true,true,false,true><<<GGRID, 256, 0, stream>>>((const unsigned short*)aggB, wt + 4096,
                                                                         b1, ndst, bufA, spart + 1*NPAGE*256);
    k_bnfin<<<1, 128, 0, stream>>>(spart + 1*NPAGE*256, stats + 1*512, g1, bt1);
    k_bnapply_bf<<<(NN*64 + 255)/256, 256, 0, stream>>>((unsigned*)bufA, stats + 1*512, nsrc, bufC);

    // ---- layer 2 ----
    k_agg_bf<<<NN, 256, 0, stream>>>((const uint4*)bufC, offsets, degi, csr, aggB);
    k_gemm_mfma<128,128,true,true,false,true><<<GGRID, 256, 0, stream>>>((const unsigned short*)aggB, wt + 20480,
                                                                         b2, ndst, bufA, spart + 2*NPAGE*256);
    k_bnfin<<<1, 128, 0, stream>>>(spart + 2*NPAGE*256, stats + 2*512, g2, bt2);
    k_bnapply_bf<<<(NN*64 + 255)/256, 256, 0, stream>>>((unsigned*)bufA, stats + 2*512, nullptr, bufC);

    // ---- FC: out = x @ wfc + bfc (sliced A) ----
    k_gemm_mfma<128,64,false,false,true,true><<<GGRID, 256, 0, stream>>>((unsigned short*)bufC, wt + 36864, bfc,
                                                                         nullptr, out, nullptr);
}

// Round 15
// 337.504 us; speedup vs baseline: 1.5523x; 1.5523x over previous
//
#include <hip/hip_runtime.h>

#define NN 100000
#define NE 1600000
#define BN_EPS 1e-5f
#define CSHIFT 9
#define NBC ((NN + 511) >> CSHIFT)   // 196 coarse buckets of 512 nodes
#define CAPC 10240                   // slots per coarse bucket (mean 8163)
#define EPB1 4096
#define NBLK1 ((NE + EPB1 - 1)/EPB1) // 391 pass-1 blocks
#define NTILES ((NN + 63)/64)        // 1563 row tiles
#define GGRID 521                    // 521*3 = 1563 exactly
#define NPAGE 64                     // stats partial pages

typedef short bf16x8 __attribute__((ext_vector_type(8)));
typedef float f32x4  __attribute__((ext_vector_type(4)));

__constant__ float c_wtab[26] = {0.7f,0.9f,0.7f,0.9f,0.3f,0.7f,0.3f,0.9f,0.3f,0.3f,0.9f,0.7f,0.1f,
                                 0.9f,0.5f,0.9f,0.5f,0.5f,0.1f,0.3f,0.7f,0.9f,0.9f,0.9f,0.9f,0.9f};

__device__ __forceinline__ unsigned f2bf(float f){
    unsigned u = __float_as_uint(f);
    return (u + 0x7fffu + ((u >> 16) & 1u)) >> 16;   // round-to-nearest-even
}
__device__ __forceinline__ float bflo(unsigned v){ return __uint_as_float(v << 16); }
__device__ __forceinline__ float bfhi(unsigned v){ return __uint_as_float(v & 0xffff0000u); }

// ---- weight prep (transpose+bf16) + cursor init, one dispatch ----
__global__ void k_prep(const float* __restrict__ w0, const float* __restrict__ w1,
                       const float* __restrict__ w2, const float* __restrict__ wfc,
                       unsigned short* __restrict__ wt,
                       unsigned* __restrict__ gcurD, unsigned* __restrict__ gcurS){
    int i = blockIdx.x*256 + threadIdx.x;
    if (i < 4096){                       // w0t: [128 cols][32 k], k>=26 zero
        int c = i >> 5, k = i & 31;
        float v = (k < 26) ? w0[k*128 + c] : 0.f;
        wt[i] = (unsigned short)f2bf(v);
    } else if (i < 20480){               // w1t: [128][128]
        int j = i - 4096; int c = j >> 7, k = j & 127;
        wt[i] = (unsigned short)f2bf(w1[k*128 + c]);
    } else if (i < 36864){               // w2t: [128][128]
        int j = i - 20480; int c = j >> 7, k = j & 127;
        wt[i] = (unsigned short)f2bf(w2[k*128 + c]);
    } else if (i < 45056){               // wfct: [64][128]
        int j = i - 36864; int c = j >> 7, k = j & 127;
        wt[i] = (unsigned short)f2bf(wfc[k*64 + c]);
    }
    if (i < NBC){ gcurD[i] = (unsigned)i*CAPC; gcurS[i] = (unsigned)i*CAPC; }
}

// ---- pass 1: coarse radix scatter, run-reserved contiguous writes ----
__global__ __launch_bounds__(512) void k_radix1(const int* __restrict__ src,
                                                const int* __restrict__ dst,
                                                unsigned* __restrict__ gcurD,
                                                unsigned* __restrict__ gcurS,
                                                unsigned* __restrict__ pairs,
                                                unsigned short* __restrict__ tok){
    __shared__ unsigned hD[NBC], hS[NBC];
    int tid = threadIdx.x;
    for (int i = tid; i < NBC; i += 512){ hD[i] = 0u; hS[i] = 0u; }
    __syncthreads();
    int base = blockIdx.x*EPB1;
    int n = NE - base; if (n > EPB1) n = EPB1;
    for (int k = tid; k < n; k += 512){
        atomicAdd(&hD[(unsigned)dst[base+k] >> CSHIFT], 1u);
        atomicAdd(&hS[(unsigned)src[base+k] >> CSHIFT], 1u);
    }
    __syncthreads();
    for (int i = tid; i < NBC; i += 512){
        unsigned c = hD[i];
        hD[i] = c ? atomicAdd(&gcurD[i], c) : 0u;
        c = hS[i];
        hS[i] = c ? atomicAdd(&gcurS[i], c) : 0u;
    }
    __syncthreads();
    for (int k = tid; k < n; k += 512){
        int d = dst[base+k], s = src[base+k];
        unsigned bb = (unsigned)d >> CSHIFT;
        unsigned p = atomicAdd(&hD[bb], 1u);
        if (p < (bb+1)*CAPC)
            pairs[p] = ((unsigned)(d & 511) << 17) | (unsigned)s;
        bb = (unsigned)s >> CSHIFT;
        p = atomicAdd(&hS[bb], 1u);
        if (p < (bb+1)*CAPC)
            tok[p] = (unsigned short)(s & 511);
    }
}

// ---- pass 2: CSR + degi + node params (norms, argmax weight, xn0), no global atomics ----
__global__ __launch_bounds__(1024) void k_radix2n(const unsigned* __restrict__ gcurD,
                                                  const unsigned* __restrict__ gcurS,
                                                  const unsigned* __restrict__ pairs,
                                                  const unsigned short* __restrict__ tok,
                                                  const float* __restrict__ h,
                                                  int* __restrict__ csr,
                                                  unsigned* __restrict__ offs,
                                                  unsigned* __restrict__ degi,
                                                  float* __restrict__ nsrc,
                                                  float* __restrict__ ndst,
                                                  float* __restrict__ outw,
                                                  unsigned* __restrict__ xn0){
    __shared__ unsigned cnt[512], cur[512], scnt[512];
    int b = blockIdx.x, tid = threadIdx.x;
    if (tid < 512){ cnt[tid] = 0u; scnt[tid] = 0u; }
    __syncthreads();
    unsigned baseC = (unsigned)b*CAPC;
    unsigned nD = gcurD[b] - baseC; if (nD > CAPC) nD = CAPC;
    unsigned nS = gcurS[b] - baseC; if (nS > CAPC) nS = CAPC;
    for (unsigned i = tid; i < nD; i += 1024)
        atomicAdd(&cnt[pairs[baseC + i] >> 17], 1u);
    for (unsigned i = tid; i < nS; i += 1024)
        atomicAdd(&scnt[tok[baseC + i]], 1u);
    __syncthreads();
    if (tid < 512) cur[tid] = cnt[tid];
    __syncthreads();
    for (int o = 1; o < 512; o <<= 1){
        unsigned x = 0;
        if (tid < 512 && tid >= o) x = cur[tid - o];
        __syncthreads();
        if (tid < 512) cur[tid] += x;
        __syncthreads();
    }
    if (tid < 512){
        unsigned ex = cur[tid] - cnt[tid];   // exclusive prefix
        int node = (b << CSHIFT) + tid;
        if (node < NN){
            offs[node] = baseC + ex;
            degi[node] = cnt[tid];
        }
        cur[tid] = ex;                       // becomes placement cursor
    }
    __syncthreads();
    for (unsigned i = tid; i < nD; i += 1024){
        unsigned pr = pairs[baseC + i];
        unsigned p = atomicAdd(&cur[pr >> 17], 1u);
        csr[baseC + p] = (int)(pr & 0x1FFFFu);
    }
    // node params (cnt/scnt stable; independent of placement)
    if (tid < 512){
        int node = (b << CSHIFT) + tid;
        if (node < NN){
            float d0 = (float)scnt[tid]; d0 = d0 < 1.f ? 1.f : d0;
            float d1 = (float)cnt[tid];  d1 = d1 < 1.f ? 1.f : d1;
            float ns = rsqrtf(d0);
            nsrc[node] = ns;
            ndst[node] = rsqrtf(d1);
            float row[26];
            #pragma unroll
            for (int c = 0; c < 26; ++c) row[c] = h[(size_t)node*26 + c];
            float best = row[0]; int bi = 0;
            #pragma unroll
            for (int c = 1; c < 26; ++c){ if (row[c] > best){ best = row[c]; bi = c; } }
            outw[node] = c_wtab[bi];
            #pragma unroll
            for (int d = 0; d < 13; ++d)
                xn0[(size_t)node*16 + d] = f2bf(row[2*d]*ns) | (f2bf(row[2*d+1]*ns) << 16);
            #pragma unroll
            for (int d = 13; d < 16; ++d) xn0[(size_t)node*16 + d] = 0u;
        }
    }
}

// ------- layer-0 aggregation: bf16 [N,32] gather (4 lanes/row x 16 groups) -> bf16 [N,32] -------
__global__ __launch_bounds__(64) void k_agg0(const uint4* __restrict__ xn,
                                             const unsigned* __restrict__ offs,
                                             const unsigned* __restrict__ degi,
                                             const int* __restrict__ csr,
                                             uint4* __restrict__ agg){
    int node = blockIdx.x;
    int lane = threadIdx.x;
    int g = lane >> 2, q = lane & 3;     // 16 edge-groups x 4 uint4-slots
    unsigned beg = offs[node], end = beg + degi[node];
    float a[8];
    #pragma unroll
    for (int j = 0; j < 8; ++j) a[j] = 0.f;
    for (unsigned e = beg + (unsigned)g; e < end; e += 16){
        uint4 v = xn[(size_t)csr[e]*4 + q];
        a[0] += bflo(v.x); a[1] += bfhi(v.x);
        a[2] += bflo(v.y); a[3] += bfhi(v.y);
        a[4] += bflo(v.z); a[5] += bfhi(v.z);
        a[6] += bflo(v.w); a[7] += bfhi(v.w);
    }
    #pragma unroll
    for (int j = 0; j < 8; ++j){
        a[j] += __shfl_xor(a[j], 4);
        a[j] += __shfl_xor(a[j], 8);
        a[j] += __shfl_xor(a[j], 16);
        a[j] += __shfl_xor(a[j], 32);
    }
    if (g == 0){
        uint4 o;
        o.x = f2bf(a[0]) | (f2bf(a[1]) << 16);
        o.y = f2bf(a[2]) | (f2bf(a[3]) << 16);
        o.z = f2bf(a[4]) | (f2bf(a[5]) << 16);
        o.w = f2bf(a[6]) | (f2bf(a[7]) << 16);
        agg[(size_t)node*4 + q] = o;
    }
}

// ---- layers 1/2 aggregation WITH fused BN+ReLU+nsrc on gather ----
// gathers raw z (bf16 [N,128]); val = relu(z*sc+sh)*nsrc[s]; r13 structure (16 lanes/row, 4 groups).
__global__ __launch_bounds__(64) void k_agg_bn(const uint4* __restrict__ zt,
                                               const float* __restrict__ st,   // [256+c]=sc,[384+c]=sh
                                               const float* __restrict__ nsrc,
                                               const unsigned* __restrict__ offs,
                                               const unsigned* __restrict__ degi,
                                               const int* __restrict__ csr,
                                               uint4* __restrict__ agg){
    int node = blockIdx.x;
    int lane = threadIdx.x;
    int g = lane >> 4, q = lane & 15;    // group = edge slot, q = uint4 index in row
    float sc8[8], sh8[8];
    #pragma unroll
    for (int j = 0; j < 8; ++j){
        sc8[j] = st[256 + q*8 + j];
        sh8[j] = st[384 + q*8 + j];
    }
    unsigned beg = offs[node], end = beg + degi[node];
    float a[8];
    #pragma unroll
    for (int j = 0; j < 8; ++j) a[j] = 0.f;
    unsigned e = beg + (unsigned)g;
    for (; e + 12 < end; e += 16){
        int s0 = csr[e], s1 = csr[e+4], s2 = csr[e+8], s3 = csr[e+12];
        float n0 = nsrc[s0], n1 = nsrc[s1], n2 = nsrc[s2], n3 = nsrc[s3];
        uint4 v0 = zt[(size_t)s0*16 + q];
        uint4 v1 = zt[(size_t)s1*16 + q];
        uint4 v2 = zt[(size_t)s2*16 + q];
        uint4 v3 = zt[(size_t)s3*16 + q];
        #pragma unroll
        for (int k = 0; k < 4; ++k){
            uint4 v = (k==0)?v0:(k==1)?v1:(k==2)?v2:v3;
            float nn = (k==0)?n0:(k==1)?n1:(k==2)?n2:n3;
            float t;
            t = fmaf(bflo(v.x), sc8[0], sh8[0]); t = t > 0.f ? t : 0.f; a[0] = fmaf(t, nn, a[0]);
            t = fmaf(bfhi(v.x), sc8[1], sh8[1]); t = t > 0.f ? t : 0.f; a[1] = fmaf(t, nn, a[1]);
            t = fmaf(bflo(v.y), sc8[2], sh8[2]); t = t > 0.f ? t : 0.f; a[2] = fmaf(t, nn, a[2]);
            t = fmaf(bfhi(v.y), sc8[3], sh8[3]); t = t > 0.f ? t : 0.f; a[3] = fmaf(t, nn, a[3]);
            t = fmaf(bflo(v.z), sc8[4], sh8[4]); t = t > 0.f ? t : 0.f; a[4] = fmaf(t, nn, a[4]);
            t = fmaf(bfhi(v.z), sc8[5], sh8[5]); t = t > 0.f ? t : 0.f; a[5] = fmaf(t, nn, a[5]);
            t = fmaf(bflo(v.w), sc8[6], sh8[6]); t = t > 0.f ? t : 0.f; a[6] = fmaf(t, nn, a[6]);
            t = fmaf(bfhi(v.w), sc8[7], sh8[7]); t = t > 0.f ? t : 0.f; a[7] = fmaf(t, nn, a[7]);
        }
    }
    for (; e < end; e += 4){
        int s = csr[e];
        float nn = nsrc[s];
        uint4 v = zt[(size_t)s*16 + q];
        float t;
        t = fmaf(bflo(v.x), sc8[0], sh8[0]); t = t > 0.f ? t : 0.f; a[0] = fmaf(t, nn, a[0]);
        t = fmaf(bfhi(v.x), sc8[1], sh8[1]); t = t > 0.f ? t : 0.f; a[1] = fmaf(t, nn, a[1]);
        t = fmaf(bflo(v.y), sc8[2], sh8[2]); t = t > 0.f ? t : 0.f; a[2] = fmaf(t, nn, a[2]);
        t = fmaf(bfhi(v.y), sc8[3], sh8[3]); t = t > 0.f ? t : 0.f; a[3] = fmaf(t, nn, a[3]);
        t = fmaf(bflo(v.z), sc8[4], sh8[4]); t = t > 0.f ? t : 0.f; a[4] = fmaf(t, nn, a[4]);
        t = fmaf(bfhi(v.z), sc8[5], sh8[5]); t = t > 0.f ? t : 0.f; a[5] = fmaf(t, nn, a[5]);
        t = fmaf(bflo(v.w), sc8[6], sh8[6]); t = t > 0.f ? t : 0.f; a[6] = fmaf(t, nn, a[6]);
        t = fmaf(bfhi(v.w), sc8[7], sh8[7]); t = t > 0.f ? t : 0.f; a[7] = fmaf(t, nn, a[7]);
    }
    #pragma unroll
    for (int j = 0; j < 8; ++j){
        a[j] += __shfl_xor(a[j], 16);
        a[j] += __shfl_xor(a[j], 32);
    }
    if (g == 0){
        uint4 o;
        o.x = f2bf(a[0]) | (f2bf(a[1]) << 16);
        o.y = f2bf(a[2]) | (f2bf(a[3]) << 16);
        o.z = f2bf(a[4]) | (f2bf(a[5]) << 16);
        o.w = f2bf(a[6]) | (f2bf(a[7]) << 16);
        agg[(size_t)node*16 + q] = o;
    }
}

// ---------------- MFMA GEMM (grid-strided): Z = A(bf16) @ Bt^T (*ndst) + bias ----------------
// BNIN: apply BN+ReLU to A during staging (for FC). Stats in registers, one paged flush.
template<int CIN, int COUT, bool STATS, bool NDST, bool F32OUT, bool BNIN>
__global__ __launch_bounds__(256) void k_gemm_mfma(const unsigned short* __restrict__ A,
                                                   const unsigned short* __restrict__ Bt,
                                                   const float* __restrict__ bias,
                                                   const float* __restrict__ ndst,
                                                   void* __restrict__ Zv,
                                                   float* __restrict__ part,
                                                   const float* __restrict__ bn){
    constexpr int KD4 = CIN/8;    // uint4 per row
    constexpr int NT = COUT/16;   // 16-col tiles per wave
    __shared__ char sA[64*CIN*2];
    __shared__ char sB[COUT*CIN*2];
    __shared__ float sS[2][COUT];
    float* Zf = (float*)Zv;
    unsigned short* Zh = (unsigned short*)Zv;
    const int tid = threadIdx.x;
    const int w = tid >> 6, lane = tid & 63;
    const int lrow = lane & 15, kg = lane >> 4;

    const uint4* B4 = (const uint4*)Bt;
    for (int i = tid; i < COUT*KD4; i += 256){
        int cc = i/KD4, c4 = i - cc*KD4;
        *(uint4*)(sB + ((cc*CIN*2 + c4*16) ^ ((cc&7)<<4))) = B4[i];
    }
    if (STATS){
        for (int i = tid; i < 2*COUT; i += 256) (&sS[0][0])[i] = 0.f;
    }

    float cs[NT], cq[NT];
    #pragma unroll
    for (int n = 0; n < NT; ++n){ cs[n] = 0.f; cq[n] = 0.f; }

    const uint4* A4 = (const uint4*)A;
    const uint4 z4 = make_uint4(0,0,0,0);
    for (int t = blockIdx.x; t < NTILES; t += GGRID){
        const int row0 = t*64;
        for (int i = tid; i < 64*KD4; i += 256){
            int r = i/KD4, c4 = i - r*KD4;
            int gr = row0 + r;
            uint4 v = (gr < NN) ? A4[(size_t)gr*KD4 + c4] : z4;
            if (BNIN && gr < NN){
                int ch = c4*8;
                unsigned dw[4] = {v.x, v.y, v.z, v.w};
                #pragma unroll
                for (int k = 0; k < 4; ++k){
                    float f0 = fmaf(bflo(dw[k]), bn[256 + ch + 2*k],     bn[384 + ch + 2*k]);
                    float f1 = fmaf(bfhi(dw[k]), bn[256 + ch + 2*k + 1], bn[384 + ch + 2*k + 1]);
                    f0 = f0 > 0.f ? f0 : 0.f;
                    f1 = f1 > 0.f ? f1 : 0.f;
                    dw[k] = f2bf(f0) | (f2bf(f1) << 16);
                }
                v = make_uint4(dw[0], dw[1], dw[2], dw[3]);
            }
            *(uint4*)(sA + ((r*CIN*2 + c4*16) ^ ((r&7)<<4))) = v;
        }
        __syncthreads();
        f32x4 acc[NT];
        #pragma unroll
        for (int n = 0; n < NT; ++n) acc[n] = (f32x4){0.f,0.f,0.f,0.f};
        const int arow = w*16 + lrow;
        #pragma unroll
        for (int kk = 0; kk < CIN/32; ++kk){
            const int kb = kk*64 + kg*16;
            bf16x8 af = *(const bf16x8*)(sA + ((arow*CIN*2 + kb) ^ ((arow&7)<<4)));
            #pragma unroll
            for (int n = 0; n < NT; ++n){
                int bc = n*16 + lrow;
                bf16x8 bv = *(const bf16x8*)(sB + ((bc*CIN*2 + kb) ^ ((bc&7)<<4)));
                acc[n] = __builtin_amdgcn_mfma_f32_16x16x32_bf16(af, bv, acc[n], 0, 0, 0);
            }
        }
        // epilogue: C/D mapping col=lane&15, row=(lane>>4)*4+j  [m89-verified]
        int grow[4]; float nm[4]; bool val[4];
        #pragma unroll
        for (int j = 0; j < 4; ++j){
            grow[j] = row0 + w*16 + kg*4 + j;
            val[j]  = grow[j] < NN;
            nm[j]   = (NDST && val[j]) ? ndst[grow[j]] : 1.f;
        }
        #pragma unroll
        for (int n = 0; n < NT; ++n){
            int gcol = n*16 + lrow;
            float bv = bias[gcol];
            #pragma unroll
            for (int j = 0; j < 4; ++j){
                float z = acc[n][j]*nm[j] + bv;
                if (val[j]){
                    if (F32OUT) Zf[(size_t)grow[j]*COUT + gcol] = z;
                    else        Zh[(size_t)grow[j]*COUT + gcol] = (unsigned short)f2bf(z);
                    if (STATS){ cs[n] += z; cq[n] += z*z; }
                }
            }
        }
        __syncthreads();
    }
    if (STATS){
        #pragma unroll
        for (int n = 0; n < NT; ++n){
            float s = cs[n], q = cq[n];
            s += __shfl_xor(s, 16); s += __shfl_xor(s, 32);
            q += __shfl_xor(q, 16); q += __shfl_xor(q, 32);
            if (kg == 0){
                atomicAdd(&sS[0][n*16 + lrow], s);
                atomicAdd(&sS[1][n*16 + lrow], q);
            }
        }
        __syncthreads();
        float* pg = part + (size_t)(blockIdx.x & (NPAGE-1))*2*COUT;
        for (int i = tid; i < 2*COUT; i += 256)
            atomicAdd(&pg[i], (&sS[0][0])[i]);
    }
}

// ---------------- BN finalize: reduce partial pages -> scale/shift ----------------
__global__ void k_bnfin(const float* __restrict__ part, float* __restrict__ stats,
                        const float* __restrict__ g, const float* __restrict__ bt){
    int c = threadIdx.x;  // 128
    float s = 0.f, q = 0.f;
    #pragma unroll 8
    for (int p = 0; p < NPAGE; ++p){
        s += part[p*256 + c];
        q += part[p*256 + 128 + c];
    }
    float mu  = s / (float)NN;
    float var = q / (float)NN - mu*mu;
    if (var < 0.f) var = 0.f;
    float sc = g[c] * rsqrtf(var + BN_EPS);
    stats[256 + c] = sc;
    stats[384 + c] = bt[c] - mu*sc;
}

extern "C" void kernel_launch(void* const* d_in, const int* in_sizes, int n_in,
                              void* d_out, int out_size, void* d_ws, size_t ws_size,
                              hipStream_t stream) {
    const float* h   = (const float*)d_in[0];
    const int*   src = (const int*)d_in[1];
    const int*   dst = (const int*)d_in[2];
    const float* w0  = (const float*)d_in[3];
    const float* b0  = (const float*)d_in[4];
    const float* w1  = (const float*)d_in[5];
    const float* b1  = (const float*)d_in[6];
    const float* w2  = (const float*)d_in[7];
    const float* b2  = (const float*)d_in[8];
    const float* g0  = (const float*)d_in[9];
    const float* bt0 = (const float*)d_in[10];
    const float* g1  = (const float*)d_in[11];
    const float* bt1 = (const float*)d_in[12];
    const float* g2  = (const float*)d_in[13];
    const float* bt2 = (const float*)d_in[14];
    const float* wfc = (const float*)d_in[15];
    const float* bfc = (const float*)d_in[16];

    float* out   = (float*)d_out;                     // [NN,64]
    float* out_w = out + (size_t)NN*64;               // [NN,1]

    char* ws = (char*)d_ws;
    size_t off = 0;
    auto alloc = [&](size_t b){ size_t p = off; off += (b + 255) & ~(size_t)255; return ws + p; };

    unsigned*       degi    = (unsigned*)alloc((size_t)NN*4);
    float*          nsrc    = (float*)   alloc((size_t)NN*4);
    float*          ndst    = (float*)   alloc((size_t)NN*4);
    unsigned*       offsets = (unsigned*)alloc((size_t)NN*4);
    unsigned*       gcurD   = (unsigned*)alloc((size_t)NBC*4);
    unsigned*       gcurS   = (unsigned*)alloc((size_t)NBC*4);
    float*          stats   = (float*)   alloc(3*512*4);            // scale/shift per layer
    float*          spart   = (float*)   alloc(3*(size_t)NPAGE*256*4); // stats partial pages
    unsigned short* wt      = (unsigned short*)alloc(45056*2);  // bf16 transposed weights
    int*            csr     = (int*)     alloc((size_t)NBC*CAPC*4);   // 8 MB exact CSR
    unsigned*       xn0     = (unsigned*)alloc((size_t)NN*16*4);      // bf16 [N,32] scaled h
    unsigned short* bufA    = (unsigned short*)alloc((size_t)NN*128*2); // GEMM out z (bf16 pre-BN)
    float*          bufB    = (float*)   alloc((size_t)NN*128*4);   // radix scratch / agg out
    (void)ws_size; (void)in_sizes; (void)n_in; (void)out_size;

    unsigned*       pairs = (unsigned*)bufB;                          // 8 MB
    unsigned short* tok   = (unsigned short*)((char*)bufB + (size_t)NBC*CAPC*4); // 4 MB
    uint4*          aggB  = (uint4*)bufB;   // agg outputs (radix scratch dead by then)

    hipMemsetAsync(spart, 0, 3*(size_t)NPAGE*256*4, stream);

    // ---- build: prep + 2-pass coarse radix (CSR + degrees + node params) ----
    k_prep<<<176, 256, 0, stream>>>(w0, w1, w2, wfc, wt, gcurD, gcurS);
    k_radix1<<<NBLK1, 512, 0, stream>>>(src, dst, gcurD, gcurS, pairs, tok);
    k_radix2n<<<NBC, 1024, 0, stream>>>(gcurD, gcurS, pairs, tok, h, csr, offsets, degi,
                                        nsrc, ndst, out_w, xn0);

    // ---- layer 0: gather-agg -> gemm 32x128 (z0 -> bufA) ----
    k_agg0<<<NN, 64, 0, stream>>>((const uint4*)xn0, offsets, degi, csr, aggB);
    k_gemm_mfma<32,128,true,true,false,false><<<GGRID, 256, 0, stream>>>(
        (const unsigned short*)aggB, wt, b0, ndst, bufA, spart + 0*NPAGE*256, nullptr);
    k_bnfin<<<1, 128, 0, stream>>>(spart + 0*NPAGE*256, stats + 0*512, g0, bt0);

    // ---- layer 1: BN-on-gather agg -> gemm (z1 -> bufA) ----
    k_agg_bn<<<NN, 64, 0, stream>>>((const uint4*)bufA, stats + 0*512, nsrc,
                                    offsets, degi, csr, aggB);
    k_gemm_mfma<128,128,true,true,false,false><<<GGRID, 256, 0, stream>>>(
        (const unsigned short*)aggB, wt + 4096, b1, ndst, bufA, spart + 1*NPAGE*256, nullptr);
    k_bnfin<<<1, 128, 0, stream>>>(spart + 1*NPAGE*256, stats + 1*512, g1, bt1);

    // ---- layer 2 ----
    k_agg_bn<<<NN, 64, 0, stream>>>((const uint4*)bufA, stats + 1*512, nsrc,
                                    offsets, degi, csr, aggB);
    k_gemm_mfma<128,128,true,true,false,false><<<GGRID, 256, 0, stream>>>(
        (const unsigned short*)aggB, wt + 20480, b2, ndst, bufA, spart + 2*NPAGE*256, nullptr);
    k_bnfin<<<1, 128, 0, stream>>>(spart + 2*NPAGE*256, stats + 2*512, g2, bt2);

    // ---- FC: BN+ReLU applied in staging; out = relu(bn(z2)) @ wfc + bfc ----
    k_gemm_mfma<128,64,false,false,true,true><<<GGRID, 256, 0, stream>>>(
        bufA, wt + 36864, bfc, nullptr, out, nullptr, stats + 2*512);
}